// Round 9
// baseline (377.468 us; speedup 1.0000x reference)
//
#include <hip/hip_runtime.h>
#include <hip/hip_bf16.h>
#include <stdint.h>

#define N_TOK 16384
#define D_IN  2048
#define D_HID 2048

typedef __attribute__((ext_vector_type(8)))  short bf16x8;
typedef __attribute__((ext_vector_type(16))) float f32x16;
typedef __attribute__((ext_vector_type(8)))  unsigned short u16x8;

__device__ __forceinline__ unsigned short f2bf(float f) {
    unsigned int u = __float_as_uint(f);
    u = (u + 0x7FFFu + ((u >> 16) & 1u)) >> 16;
    return (unsigned short)u;
}

// ------------------------- fused prep: xconv slabs + gate (role-split) ----
// blocks 0..4095: x -> bf16 slab order (same as R6, proven).
// blocks 4096..4607: gate, 32 tokens/block (8/wave), W_gate read once per
// wave (8x less L2 traffic than 1-token-per-wave), x reads lane-coalesced.
__global__ __launch_bounds__(256) void prep_kernel(
    const float* __restrict__ x,
    const float* __restrict__ Wg,
    const float* __restrict__ bg,
    unsigned short* __restrict__ xb,
    float* __restrict__ s12,
    int* __restrict__ eidx) {
    const int bid = blockIdx.x;
    if (bid < 4096) {
        const int mt = bid >> 6;
        const int kt = bid & 63;
        const int t  = threadIdx.x;
        const float* src = x + ((size_t)(mt * 256 + t)) * D_IN + kt * 32;
        unsigned short* slab = xb + ((size_t)(mt * 64 + kt)) * 8192;
#pragma unroll
        for (int ks = 0; ks < 4; ++ks) {
            float4 a = *(const float4*)(src + ks * 8);
            float4 b = *(const float4*)(src + ks * 8 + 4);
            u16x8 v;
            v[0] = f2bf(a.x); v[1] = f2bf(a.y); v[2] = f2bf(a.z); v[3] = f2bf(a.w);
            v[4] = f2bf(b.x); v[5] = f2bf(b.y); v[6] = f2bf(b.z); v[7] = f2bf(b.w);
            *(u16x8*)(slab + (ks * 256 + t) * 8) = v;
        }
        return;
    }
    // ---- gate role ----
    const int gb   = bid - 4096;
    const int w    = threadIdx.x >> 6;
    const int lane = threadIdx.x & 63;
    const int tbase = gb * 32 + w * 8;

    float acc[8][8];
#pragma unroll
    for (int tok = 0; tok < 8; ++tok)
#pragma unroll
        for (int e = 0; e < 8; ++e) acc[tok][e] = 0.f;

    for (int i = lane; i < D_IN; i += 64) {
        const float4* wr = (const float4*)(Wg + (size_t)i * 8);
        float4 w0 = wr[0], w1 = wr[1];
#pragma unroll
        for (int tok = 0; tok < 8; ++tok) {
            float xv = x[(size_t)(tbase + tok) * D_IN + i];
            acc[tok][0] += xv * w0.x; acc[tok][1] += xv * w0.y;
            acc[tok][2] += xv * w0.z; acc[tok][3] += xv * w0.w;
            acc[tok][4] += xv * w1.x; acc[tok][5] += xv * w1.y;
            acc[tok][6] += xv * w1.z; acc[tok][7] += xv * w1.w;
        }
    }
#pragma unroll
    for (int off = 32; off > 0; off >>= 1)
#pragma unroll
        for (int tok = 0; tok < 8; ++tok)
#pragma unroll
            for (int e = 0; e < 8; ++e)
                acc[tok][e] += __shfl_xor(acc[tok][e], off);

    if (lane == 0) {
#pragma unroll
        for (int tok = 0; tok < 8; ++tok) {
            float lg[8];
            float mx = -1e30f;
#pragma unroll
            for (int e = 0; e < 8; ++e) {
                lg[e] = acc[tok][e] + bg[e];
                mx = fmaxf(mx, lg[e]);
            }
            float sum = 0.f;
#pragma unroll
            for (int e = 0; e < 8; ++e) { lg[e] = expf(lg[e] - mx); sum += lg[e]; }
            float inv = 1.f / sum;
            float s1 = -1.f, s2 = -1.f; int i1 = 0, i2 = 0;
#pragma unroll
            for (int e = 0; e < 8; ++e) {
                float g = lg[e] * inv;
                if (g > s1)      { s2 = s1; i2 = i1; s1 = g; i1 = e; }
                else if (g > s2) { s2 = g;  i2 = e; }
            }
            const int token = tbase + tok;
            s12[token * 2]     = s1;
            s12[token * 2 + 1] = s2;
            if (token == 0) { eidx[0] = i1; eidx[1] = i2; }
        }
    }
}

// --------------------- W[e0],W[e1] -> bf16 slab order (transposed) --------
__global__ void wconv_kernel(const float* __restrict__ W,
                             const int* __restrict__ eidx,
                             unsigned short* __restrict__ wbT) {
    __shared__ float tile[64][65];
    const int be  = blockIdx.z;
    const int e   = eidx[be];
    const int k0  = blockIdx.y * 64;
    const int n0  = blockIdx.x * 64;
    const int bx  = n0 >> 7;
    const int cl0 = n0 & 127;
    const int kt0 = k0 >> 5;
    const float* src = W + (size_t)e * D_IN * D_HID;
    const int t = threadIdx.x;

#pragma unroll
    for (int p = 0; p < 4; ++p) {
        int row = p * 16 + (t >> 4);
        int col = (t & 15) * 4;
        const float* s = src + (size_t)(k0 + row) * D_HID + n0 + col;
        tile[row][col]     = s[0];
        tile[row][col + 1] = s[1];
        tile[row][col + 2] = s[2];
        tile[row][col + 3] = s[3];
    }
    __syncthreads();

    const int g   = (t >> 5) * 8;
    const int ktl = t >> 7;
    const int ks  = (t >> 5) & 3;
#pragma unroll
    for (int p = 0; p < 2; ++p) {
        int n = p * 32 + (t & 31);
        u16x8 v;
#pragma unroll
        for (int j = 0; j < 8; ++j) v[j] = f2bf(tile[g + j][n]);
        unsigned short* dst = wbT + ((size_t)(bx * 64 + kt0 + ktl)) * 8192 +
                              ((size_t)(ks * 256 + be * 128 + cl0 + n)) * 8;
        *(u16x8*)dst = v;
    }
}

// ------------------------------------------------------------------ GEMM --
// 4 waves (256 thr), wave tile 128x128 (2M x 2N), 32x32x16 MFMA (R4-proven
// frag/epilogue mapping), BK=32. Fragment reads drop 96->64 KB per K-tile
// -> LDS (~900 cyc) under MFMA floor (~1126 cyc): MFMA-bound regime.
// 4 LDS buffers x 32 KB = 128 KiB, depth-3 staging, vmcnt(16) steady
// (retires t+1, leaves t+2/t+3 in flight), ONE barrier per tile. acc 256 +
// frags 64 VGPR -> 1 wave/SIMD; latency hiding via ILP (16 reads ahead of
// 32 independent-acc MFMAs, compiler per-frag lgkm gating).
#define GLD16(gp, lp)                                                        \
    __builtin_amdgcn_global_load_lds(                                        \
        (const __attribute__((address_space(1))) void*)(gp),                 \
        (__attribute__((address_space(3))) void*)(lp), 16, 0, 0)

#define LDSV(SLOT) (*(const bf16x8*)&lds[(SLOT) * 8])

#define STAGE(BUF, KT)                                                       \
    do {                                                                     \
        _Pragma("unroll")                                                    \
        for (int j = 0; j < 4; ++j) {                                        \
            GLD16(gA0 + (size_t)(KT) * 8192 + j * 2048,                      \
                  &lds[((BUF) * 2048 + j * 256 + t256) * 8]);                \
            GLD16(gB0 + (size_t)(KT) * 8192 + j * 2048,                      \
                  &lds[((BUF) * 2048 + 1024 + j * 256 + t256) * 8]);         \
        }                                                                    \
    } while (0)

#define TILE(BUF, STGT, DOSTAGE, VMSTR)                                      \
    do {                                                                     \
        __builtin_amdgcn_s_barrier();                                        \
        if (DOSTAGE) STAGE((STGT) & 3, STGT);                                \
        bf16x8 af[2][4], bf[2][4];                                           \
        _Pragma("unroll")                                                    \
        for (int kk = 0; kk < 2; ++kk)                                       \
            _Pragma("unroll")                                                \
            for (int q = 0; q < 4; ++q) {                                    \
                af[kk][q] = LDSV((BUF) * 2048 + abase + kk * 512 + q * 32);  \
                bf[kk][q] = LDSV((BUF) * 2048 + bbase + kk * 512 + q * 32);  \
            }                                                                \
        if (VMSTR[0]) asm volatile(VMSTR ::: "memory");                      \
        __builtin_amdgcn_s_setprio(1);                                       \
        _Pragma("unroll")                                                    \
        for (int kk = 0; kk < 2; ++kk)                                       \
            _Pragma("unroll")                                                \
            for (int mi = 0; mi < 4; ++mi)                                   \
                _Pragma("unroll")                                            \
                for (int ni = 0; ni < 4; ++ni)                               \
                    acc[mi][ni] = __builtin_amdgcn_mfma_f32_32x32x16_bf16(   \
                        af[kk][mi], bf[kk][ni], acc[mi][ni], 0, 0, 0);       \
        __builtin_amdgcn_s_setprio(0);                                       \
    } while (0)

#define VM16 "s_waitcnt vmcnt(16)"

__global__ __launch_bounds__(256, 1) void moe_gemm_kernel(
    const unsigned short* __restrict__ xb,   // slab order [mt64][kt64][1024]
    const unsigned short* __restrict__ wbT,  // slab order [bx16][kt64][1024]
    const float* __restrict__ b_exp,         // [8][D_HID]
    const int* __restrict__ eidx,
    const float* __restrict__ s12,           // [N_TOK][2]
    float* __restrict__ out) {
    // 4 buffers x (A 1024 + B 1024 granules) x 16B = 128 KiB
    __shared__ __align__(16) short lds[8192 * 8];

    const int t256 = threadIdx.x;
    const int lane = t256 & 63;
    const int w    = t256 >> 6;
    const int wm   = w >> 1;      // row half
    const int wn   = w & 1;       // 0: expert0 cols, 1: expert1 cols
    const int ls   = lane >> 5;
    const int lr   = lane & 31;

    // XCD swizzle: each XCD owns a bx pair (B slabs L2-resident)
    const int bid = blockIdx.x;
    const int xcd = bid & 7;
    const int jb  = bid >> 3;
    const int bx  = xcd * 2 + (jb & 1);
    const int by  = jb >> 1;
    const int mbase = by * 256;
    const int nbase = bx * 128;

    const unsigned short* gA0 = xb  + ((size_t)by * 64) * 8192 + t256 * 8;
    const unsigned short* gB0 = wbT + ((size_t)bx * 64) * 8192 + t256 * 8;

    // frag slot bases (granule units): slot = ks*256 + row
    const int abase = ls * 256 + wm * 128 + lr;          // + kk*512 + mi*32
    const int bbase = 1024 + ls * 256 + wn * 128 + lr;   // + kk*512 + ni*32

    f32x16 acc[4][4];
#pragma unroll
    for (int mi = 0; mi < 4; ++mi)
#pragma unroll
        for (int ni = 0; ni < 4; ++ni)
#pragma unroll
            for (int r = 0; r < 16; ++r) acc[mi][ni][r] = 0.f;

    // prologue: stage tiles 0,1,2; vmcnt(16) retires tile 0.
    STAGE(0, 0);
    STAGE(1, 1);
    STAGE(2, 2);
    asm volatile(VM16 ::: "memory");

    for (int t = 0; t < 60; t += 4) {
        TILE(0, t + 3, 1, VM16);
        TILE(1, t + 4, 1, VM16);
        TILE(2, t + 5, 1, VM16);
        TILE(3, t + 6, 1, VM16);
    }
    TILE(0, 63, 1, VM16);                     // tile 60, stages 63
    TILE(1, 0, 0, "s_waitcnt vmcnt(8)");      // tile 61
    TILE(2, 0, 0, "s_waitcnt vmcnt(0)");      // tile 62
    TILE(3, 0, 0, "");                        // tile 63

    // -------- epilogue: combine experts through LDS (f32) --------
    // 32x32 C/D layout (R4-verified): row=(r&3)+8*(r>>2)+4*ls, col=lr.
    __syncthreads();
    float* fl = (float*)lds;
    if (wn == 1) {
        float* reg = fl + wm * 16384;   // [128][128]
#pragma unroll
        for (int mi = 0; mi < 4; ++mi)
#pragma unroll
            for (int ni = 0; ni < 4; ++ni)
#pragma unroll
                for (int r = 0; r < 16; ++r) {
                    int row_l = mi * 32 + (r & 3) + 8 * (r >> 2) + 4 * ls;
                    reg[row_l * 128 + ni * 32 + lr] = acc[mi][ni][r];
                }
    }
    __syncthreads();
    if (wn == 0) {
        const float* reg = fl + wm * 16384;
        const int e0 = eidx[0], e1 = eidx[1];
        const float* bb0 = b_exp + (size_t)e0 * D_HID;
        const float* bb1 = b_exp + (size_t)e1 * D_HID;
        const float2* s12v = (const float2*)s12;
        int   cc[4];
        float b0c[4], b1c[4];
#pragma unroll
        for (int ni = 0; ni < 4; ++ni) {
            cc[ni]  = nbase + ni * 32 + lr;
            b0c[ni] = bb0[cc[ni]];
            b1c[ni] = bb1[cc[ni]];
        }
#pragma unroll
        for (int mi = 0; mi < 4; ++mi)
#pragma unroll
            for (int r = 0; r < 16; ++r) {
                int row_l = mi * 32 + (r & 3) + 8 * (r >> 2) + 4 * ls;
                int rg = mbase + wm * 128 + row_l;
                float2 s = s12v[rg];
#pragma unroll
                for (int ni = 0; ni < 4; ++ni) {
                    float y1 = reg[row_l * 128 + ni * 32 + lr];
                    out[(size_t)rg * D_HID + cc[ni]] =
                        s.x * (acc[mi][ni][r] + b0c[ni]) + s.y * (y1 + b1c[ni]);
                }
            }
    }
}

// ---------------------------------------------------------------- launch --
extern "C" void kernel_launch(void* const* d_in, const int* in_sizes, int n_in,
                              void* d_out, int out_size, void* d_ws, size_t ws_size,
                              hipStream_t stream) {
    const float* x         = (const float*)d_in[0];
    const float* W_experts = (const float*)d_in[1];
    const float* b_experts = (const float*)d_in[2];
    const float* W_gate    = (const float*)d_in[3];
    const float* b_gate    = (const float*)d_in[4];
    float* out = (float*)d_out;

    char* ws = (char*)d_ws;
    float* s12  = (float*)ws;                                        // 128 KiB
    int*   eidx = (int*)(ws + 131072);
    unsigned short* xb  = (unsigned short*)(ws + 262144);            // 64 MiB
    unsigned short* wbT = (unsigned short*)(ws + 262144 + 67108864); // 16 MiB

    prep_kernel<<<4608, 256, 0, stream>>>(x, W_gate, b_gate, xb, s12, eidx);
    wconv_kernel<<<dim3(32, 32, 2), 256, 0, stream>>>(W_experts, eidx, wbT);
    moe_gemm_kernel<<<1024, 256, 0, stream>>>(xb, wbT, b_experts, eidx, s12, out);
}

// Round 10
// 332.767 us; speedup vs baseline: 1.1343x; 1.1343x over previous
//
#include <hip/hip_runtime.h>
#include <hip/hip_bf16.h>
#include <stdint.h>

#define N_TOK 16384
#define D_IN  2048
#define D_HID 2048

typedef __attribute__((ext_vector_type(8))) short  bf16x8;
typedef __attribute__((ext_vector_type(4))) float  f32x4;
typedef __attribute__((ext_vector_type(8))) unsigned short u16x8;

__device__ __forceinline__ unsigned short f2bf(float f) {
    unsigned int u = __float_as_uint(f);
    u = (u + 0x7FFFu + ((u >> 16) & 1u)) >> 16;
    return (unsigned short)u;
}

// ------------------------------------------ gate0: token-0 expert indices --
__global__ void gate0_kernel(const float* __restrict__ x,
                             const float* __restrict__ Wg,
                             const float* __restrict__ bg,
                             int* __restrict__ eidx) {
    const int lane = threadIdx.x;
    float acc[8];
#pragma unroll
    for (int e = 0; e < 8; ++e) acc[e] = 0.f;
    for (int i = lane; i < D_IN; i += 64) {
        float xv = x[i];
        const float4* wr = (const float4*)(Wg + (size_t)i * 8);
        float4 w0 = wr[0], w1 = wr[1];
        acc[0] += xv * w0.x; acc[1] += xv * w0.y;
        acc[2] += xv * w0.z; acc[3] += xv * w0.w;
        acc[4] += xv * w1.x; acc[5] += xv * w1.y;
        acc[6] += xv * w1.z; acc[7] += xv * w1.w;
    }
#pragma unroll
    for (int off = 32; off > 0; off >>= 1)
#pragma unroll
        for (int e = 0; e < 8; ++e) acc[e] += __shfl_xor(acc[e], off);
    if (lane == 0) {
        float s1 = -1e30f, s2 = -1e30f; int i1 = 0, i2 = 0;
#pragma unroll
        for (int e = 0; e < 8; ++e) {
            float g = acc[e] + bg[e];
            if (g > s1)      { s2 = s1; i2 = i1; s1 = g; i1 = e; }
            else if (g > s2) { s2 = g;  i2 = e; }
        }
        eidx[0] = i1; eidx[1] = i2;
    }
}

// --------------- fused prep: xconv slabs | gate s12 | wconv (role-split) ---
// blocks 0..4095: x -> bf16 slab order (proven R6 pattern).
// blocks 4096..4607: gate s12 for all tokens (8 tokens/wave, f32 path).
// blocks 4608..6655: W[e0],W[e1] -> bf16 slab order (needs eidx from gate0).
__global__ __launch_bounds__(256) void prep_kernel(
    const float* __restrict__ x,
    const float* __restrict__ Wg,
    const float* __restrict__ bg,
    const float* __restrict__ W,
    const int* __restrict__ eidx,
    unsigned short* __restrict__ xb,
    float* __restrict__ s12,
    unsigned short* __restrict__ wbT) {
    __shared__ float tile[64][65];
    const int bid = blockIdx.x;
    if (bid < 4096) {
        const int mt = bid >> 6;
        const int kt = bid & 63;
        const int t  = threadIdx.x;
        const float* src = x + ((size_t)(mt * 256 + t)) * D_IN + kt * 32;
        unsigned short* slab = xb + ((size_t)(mt * 64 + kt)) * 8192;
#pragma unroll
        for (int ks = 0; ks < 4; ++ks) {
            float4 a = *(const float4*)(src + ks * 8);
            float4 b = *(const float4*)(src + ks * 8 + 4);
            u16x8 v;
            v[0] = f2bf(a.x); v[1] = f2bf(a.y); v[2] = f2bf(a.z); v[3] = f2bf(a.w);
            v[4] = f2bf(b.x); v[5] = f2bf(b.y); v[6] = f2bf(b.z); v[7] = f2bf(b.w);
            *(u16x8*)(slab + (ks * 256 + t) * 8) = v;
        }
        return;
    }
    if (bid < 4608) {
        // ---- gate role ----
        const int gb   = bid - 4096;
        const int w    = threadIdx.x >> 6;
        const int lane = threadIdx.x & 63;
        const int tbase = gb * 32 + w * 8;

        float acc[8][8];
#pragma unroll
        for (int tok = 0; tok < 8; ++tok)
#pragma unroll
            for (int e = 0; e < 8; ++e) acc[tok][e] = 0.f;

        for (int i = lane; i < D_IN; i += 64) {
            const float4* wr = (const float4*)(Wg + (size_t)i * 8);
            float4 w0 = wr[0], w1 = wr[1];
#pragma unroll
            for (int tok = 0; tok < 8; ++tok) {
                float xv = x[(size_t)(tbase + tok) * D_IN + i];
                acc[tok][0] += xv * w0.x; acc[tok][1] += xv * w0.y;
                acc[tok][2] += xv * w0.z; acc[tok][3] += xv * w0.w;
                acc[tok][4] += xv * w1.x; acc[tok][5] += xv * w1.y;
                acc[tok][6] += xv * w1.z; acc[tok][7] += xv * w1.w;
            }
        }
#pragma unroll
        for (int off = 32; off > 0; off >>= 1)
#pragma unroll
            for (int tok = 0; tok < 8; ++tok)
#pragma unroll
                for (int e = 0; e < 8; ++e)
                    acc[tok][e] += __shfl_xor(acc[tok][e], off);

        if (lane == 0) {
#pragma unroll
            for (int tok = 0; tok < 8; ++tok) {
                float lg[8];
                float mx = -1e30f;
#pragma unroll
                for (int e = 0; e < 8; ++e) {
                    lg[e] = acc[tok][e] + bg[e];
                    mx = fmaxf(mx, lg[e]);
                }
                float sum = 0.f;
#pragma unroll
                for (int e = 0; e < 8; ++e) { lg[e] = expf(lg[e] - mx); sum += lg[e]; }
                float inv = 1.f / sum;
                float s1 = -1.f, s2 = -1.f;
#pragma unroll
                for (int e = 0; e < 8; ++e) {
                    float g = lg[e] * inv;
                    if (g > s1)      { s2 = s1; s1 = g; }
                    else if (g > s2) { s2 = g; }
                }
                const int token = tbase + tok;
                s12[token * 2]     = s1;
                s12[token * 2 + 1] = s2;
            }
        }
        return;
    }
    // ---- wconv role ----
    const int bid2 = bid - 4608;
    const int nx   = bid2 & 31;
    const int ky   = (bid2 >> 5) & 31;
    const int be   = bid2 >> 10;
    const int e    = eidx[be];
    const int k0   = ky * 64;
    const int n0   = nx * 64;
    const int bx   = n0 >> 7;
    const int cl0  = n0 & 127;
    const int kt0  = k0 >> 5;
    const float* src = W + (size_t)e * D_IN * D_HID;
    const int t = threadIdx.x;

#pragma unroll
    for (int p = 0; p < 4; ++p) {
        int row = p * 16 + (t >> 4);
        int col = (t & 15) * 4;
        const float* s = src + (size_t)(k0 + row) * D_HID + n0 + col;
        tile[row][col]     = s[0];
        tile[row][col + 1] = s[1];
        tile[row][col + 2] = s[2];
        tile[row][col + 3] = s[3];
    }
    __syncthreads();

    const int g   = (t >> 5) * 8;
    const int ktl = t >> 7;
    const int ks  = (t >> 5) & 3;
#pragma unroll
    for (int p = 0; p < 2; ++p) {
        int n = p * 32 + (t & 31);
        u16x8 v;
#pragma unroll
        for (int j = 0; j < 8; ++j) v[j] = f2bf(tile[g + j][n]);
        unsigned short* dst = wbT + ((size_t)(bx * 64 + kt0 + ktl)) * 8192 +
                              ((size_t)(ks * 256 + be * 128 + cl0 + n)) * 8;
        *(u16x8*)dst = v;
    }
}

// ------------------------------------------------------------------ GEMM --
// 2 blocks/CU for cross-block pipe overlap (m114 mechanism): block = 128
// rows x (128 cols x 2 experts), 4 waves (wave tile 64x128), BK=32,
// 3 buffers x 24 KB = 72 KiB LDS. Per-CU traffic/MFMA density identical to
// the R6 232-us config; only the barrier domain is split. R6 double-barrier
// safety proof preserved (stage into buf[t-1] post-BAR1). vmcnt: prologue 6,
// steady 2 (retires A/B of t+1, leaves A(t+2)), tail 0.
#define GLD16(gp, lp)                                                        \
    __builtin_amdgcn_global_load_lds(                                        \
        (const __attribute__((address_space(1))) void*)(gp),                 \
        (__attribute__((address_space(3))) void*)(lp), 16, 0, 0)

#define LDSV(SLOT) (*(const bf16x8*)&lds[(SLOT) * 8])

#define STAGE_A(SB, KT)                                                      \
    do {                                                                     \
        GLD16(gA0 + (size_t)(KT) * 8192 + aoff,                              \
              &lds[((SB) * 1536 + t256) * 8]);                               \
        GLD16(gA0 + (size_t)(KT) * 8192 + aoff + 4096,                       \
              &lds[((SB) * 1536 + 256 + t256) * 8]);                         \
    } while (0)
#define STAGE_B(SB, KT)                                                      \
    do {                                                                     \
        GLD16(gB0 + (size_t)(KT) * 8192,                                     \
              &lds[((SB) * 1536 + 512 + t256) * 8]);                         \
        GLD16(gB0 + (size_t)(KT) * 8192 + 2048,                              \
              &lds[((SB) * 1536 + 768 + t256) * 8]);                         \
        GLD16(gB0 + (size_t)(KT) * 8192 + 4096,                              \
              &lds[((SB) * 1536 + 1024 + t256) * 8]);                        \
        GLD16(gB0 + (size_t)(KT) * 8192 + 6144,                              \
              &lds[((SB) * 1536 + 1280 + t256) * 8]);                        \
    } while (0)

#define MFH(NI0)                                                             \
    _Pragma("unroll")                                                        \
    for (int mi = 0; mi < 4; ++mi)                                           \
        _Pragma("unroll")                                                    \
        for (int ni = 0; ni < 4; ++ni)                                       \
            acc[mi][(NI0) + ni] = __builtin_amdgcn_mfma_f32_16x16x32_bf16(   \
                af[mi], bf[(NI0) + ni], acc[mi][(NI0) + ni], 0, 0, 0);

#define TILE(RB, SB, KT, DOSTAGE, VMSTR)                                     \
    do {                                                                     \
        const int fb = (RB) * 1536;                                          \
        bf16x8 af[4], bf[8];                                                 \
        _Pragma("unroll")                                                    \
        for (int mi = 0; mi < 4; ++mi) af[mi] = LDSV(fb + abase + mi * 16);  \
        _Pragma("unroll")                                                    \
        for (int ni = 0; ni < 8; ++ni) bf[ni] = LDSV(fb + bbase + ni * 16);  \
        __builtin_amdgcn_s_barrier();                                        \
        if (DOSTAGE) STAGE_A(SB, KT);                                        \
        __builtin_amdgcn_s_setprio(1);                                       \
        MFH(0)                                                               \
        __builtin_amdgcn_s_setprio(0);                                       \
        if (VMSTR[0]) asm volatile(VMSTR ::: "memory");                      \
        __builtin_amdgcn_s_barrier();                                        \
        if (DOSTAGE) STAGE_B(SB, KT);                                        \
        __builtin_amdgcn_s_setprio(1);                                       \
        MFH(4)                                                               \
        __builtin_amdgcn_s_setprio(0);                                       \
    } while (0)

#define VM2 "s_waitcnt vmcnt(2)"

__global__ __launch_bounds__(256, 2) void moe_gemm_kernel(
    const unsigned short* __restrict__ xb,   // slab order [mt64][kt64][1024]
    const unsigned short* __restrict__ wbT,  // slab order [bx16][kt64][1024]
    const float* __restrict__ b_exp,         // [8][D_HID]
    const int* __restrict__ eidx,
    const float* __restrict__ s12,           // [N_TOK][2]
    float* __restrict__ out) {
    // 3 buffers x (A 512 + B 1024 granules) x 16B = 72 KiB
    __shared__ __align__(16) short lds[3 * 1536 * 8];

    const int t256 = threadIdx.x;
    const int lane = t256 & 63;
    const int w    = t256 >> 6;
    const int wm   = w & 1;       // row half (64 rows)
    const int wn   = w >> 1;      // expert 0 / 1

    // XCD swizzle (2048 % 8 == 0): each XCD owns a bx pair (B L2-resident)
    const int bid = blockIdx.x;
    const int xcd = bid & 7;
    const int j   = bid >> 3;                 // 0..255
    const int bx  = xcd * 2 + (j & 1);        // 0..15
    const int by  = j >> 1;                   // 0..127
    const int mbase = by * 128;
    const int nbase = bx * 128;
    const int mt  = by >> 1;
    const int hh  = by & 1;

    const unsigned short* gA0 = xb + ((size_t)mt * 64) * 8192;
    const int aoff = (((t256 >> 7) * 256) + hh * 128 + (t256 & 127)) * 8;
    const unsigned short* gB0 = wbT + ((size_t)bx * 64) * 8192 + t256 * 8;

    // frag bases (granule units within buffer)
    const int abase = (lane >> 4) * 128 + wm * 64 + (lane & 15);
    const int bbase = 512 + (lane >> 4) * 256 + wn * 128 + (lane & 15);

    f32x4 acc[4][8];
#pragma unroll
    for (int mi = 0; mi < 4; ++mi)
#pragma unroll
        for (int ni = 0; ni < 8; ++ni) acc[mi][ni] = (f32x4){0.f, 0.f, 0.f, 0.f};

    // prologue: stage tiles 0,1; vmcnt(6) retires tile 0 (leaves A1,B1)
    STAGE_A(0, 0); STAGE_B(0, 0);
    STAGE_A(1, 1); STAGE_B(1, 1);
    asm volatile("s_waitcnt vmcnt(6)" ::: "memory");
    __builtin_amdgcn_s_barrier();

    for (int t = 0; t < 60; t += 3) {
        TILE(0, 2, t + 2, 1, VM2);
        TILE(1, 0, t + 3, 1, VM2);
        TILE(2, 1, t + 4, 1, VM2);
    }
    TILE(0, 2, 62, 1, VM2);                   // tile 60, stages 62
    TILE(1, 0, 63, 1, VM2);                   // tile 61, stages 63
    TILE(2, 0, 0, 0, "s_waitcnt vmcnt(0)");   // tile 62
    TILE(0, 0, 0, 0, "");                     // tile 63

    // -------- epilogue: combine experts through LDS (f32) --------
    __syncthreads();
    float* fl = (float*)lds;
    if (wn == 1) {
        float* reg = fl + wm * 8192;          // [64][128]
#pragma unroll
        for (int mi = 0; mi < 4; ++mi)
#pragma unroll
            for (int ni = 0; ni < 8; ++ni)
#pragma unroll
                for (int jj = 0; jj < 4; ++jj) {
                    int row_l = mi * 16 + ((lane >> 4) << 2) + jj;
                    reg[row_l * 128 + ni * 16 + (lane & 15)] = acc[mi][ni][jj];
                }
    }
    __syncthreads();
    if (wn == 0) {
        const float* reg = fl + wm * 8192;
        const int e0 = eidx[0], e1 = eidx[1];
        const float* bb0 = b_exp + (size_t)e0 * D_HID;
        const float* bb1 = b_exp + (size_t)e1 * D_HID;
        const float2* s12v = (const float2*)s12;
        int   cc[8];
        float b0c[8], b1c[8];
#pragma unroll
        for (int ni = 0; ni < 8; ++ni) {
            cc[ni]  = nbase + ni * 16 + (lane & 15);
            b0c[ni] = bb0[cc[ni]];
            b1c[ni] = bb1[cc[ni]];
        }
#pragma unroll
        for (int mi = 0; mi < 4; ++mi)
#pragma unroll
            for (int jj = 0; jj < 4; ++jj) {
                int row_l = mi * 16 + ((lane >> 4) << 2) + jj;
                int r = mbase + wm * 64 + row_l;
                float2 s = s12v[r];
#pragma unroll
                for (int ni = 0; ni < 8; ++ni) {
                    float y1 = reg[row_l * 128 + ni * 16 + (lane & 15)];
                    out[(size_t)r * D_HID + cc[ni]] =
                        s.x * (acc[mi][ni][jj] + b0c[ni]) + s.y * (y1 + b1c[ni]);
                }
            }
    }
}

// ---------------------------------------------------------------- launch --
extern "C" void kernel_launch(void* const* d_in, const int* in_sizes, int n_in,
                              void* d_out, int out_size, void* d_ws, size_t ws_size,
                              hipStream_t stream) {
    const float* x         = (const float*)d_in[0];
    const float* W_experts = (const float*)d_in[1];
    const float* b_experts = (const float*)d_in[2];
    const float* W_gate    = (const float*)d_in[3];
    const float* b_gate    = (const float*)d_in[4];
    float* out = (float*)d_out;

    char* ws = (char*)d_ws;
    float* s12  = (float*)ws;                                        // 128 KiB
    int*   eidx = (int*)(ws + 131072);
    unsigned short* xb  = (unsigned short*)(ws + 262144);            // 64 MiB
    unsigned short* wbT = (unsigned short*)(ws + 262144 + 67108864); // 16 MiB

    gate0_kernel<<<1, 64, 0, stream>>>(x, W_gate, b_gate, eidx);
    prep_kernel<<<6656, 256, 0, stream>>>(x, W_gate, b_gate, W_experts, eidx,
                                          xb, s12, wbT);
    moe_gemm_kernel<<<2048, 256, 0, stream>>>(xb, wbT, b_experts, eidx, s12, out);
}